// Round 2
// baseline (479.983 us; speedup 1.0000x reference)
//
#include <hip/hip_runtime.h>

static constexpr int NN = 32768;   // nodes
static constexpr int NE = 262144;  // edges
static constexpr int NG = 1024;    // graphs

__device__ __forceinline__ float4 ld4(const float* p){ return *reinterpret_cast<const float4*>(p); }
__device__ __forceinline__ void st4(float* p, const float4 v){ *reinterpret_cast<float4*>(p) = v; }
__device__ __forceinline__ void fma4(float4& a, const float s, const float4 w){
  a.x = fmaf(s, w.x, a.x); a.y = fmaf(s, w.y, a.y); a.z = fmaf(s, w.z, a.z); a.w = fmaf(s, w.w, a.w);
}

// ---------- h0 = nf(32768x32) @ Wn(32x64) + bn ----------
__global__ __launch_bounds__(256) void k_node_enc(const float* __restrict__ nf,
                                                  const float* __restrict__ Wn,
                                                  const float* __restrict__ bn,
                                                  float* __restrict__ h) {
  __shared__ __align__(16) float Wn_s[32*64];
  int tid = threadIdx.x;
  for (int i = tid; i < 32*64; i += 256) Wn_s[i] = Wn[i];
  __syncthreads();
  int j = tid & 63, nl = tid >> 6;
  int n = blockIdx.x*4 + nl;
  const float* r = nf + n*32;
  float acc = bn[j];
  #pragma unroll
  for (int k = 0; k < 32; ++k) acc = fmaf(r[k], Wn_s[k*64+j], acc);
  h[n*64+j] = acc;
}

// ---------- degree histogram ----------
__global__ __launch_bounds__(256) void k_hist(const int* __restrict__ toi, int* __restrict__ deg) {
  int e = blockIdx.x*256 + threadIdx.x;
  atomicAdd(&deg[toi[e]], 1);
}

// ---------- exclusive scan of deg[32768] -> rowptr[32769], single block 1024 thr ----------
__global__ __launch_bounds__(1024) void k_scan(const int* __restrict__ deg, int* __restrict__ rowptr) {
  __shared__ int sums[1024];
  int t = threadIdx.x;
  int base = t * 32;
  int local[32];
  int s = 0;
  #pragma unroll
  for (int i = 0; i < 32; ++i) { local[i] = s; s += deg[base + i]; }
  sums[t] = s;
  __syncthreads();
  for (int off = 1; off < 1024; off <<= 1) {
    int tmp = (t >= off) ? sums[t - off] : 0;
    __syncthreads();
    sums[t] += tmp;
    __syncthreads();
  }
  int boff = sums[t] - s;   // exclusive across threads
  #pragma unroll
  for (int i = 0; i < 32; ++i) rowptr[base + i] = boff + local[i];
  if (t == 1023) rowptr[NN] = sums[1023];
}

// ---------- scatter edges into CSR buckets ----------
__global__ __launch_bounds__(256) void k_scatter(const int* __restrict__ from, const int* __restrict__ toi,
                                                 const int* __restrict__ rowptr, int* __restrict__ cursor,
                                                 int2* __restrict__ csr) {
  int e = blockIdx.x*256 + threadIdx.x;
  int v = toi[e];
  int pos = atomicAdd(&cursor[v], 1);
  csr[rowptr[v] + pos] = make_int2(from[e], e);
}

// ---------- precompute folded small matrices ----------
// Wupd (64x64) = Wu[0:64] + I
// Wcomb(128x64) = Wm2 @ Wu[64:192]
// c0(64) = bm2 @ Wu[64:192]
// Wec(16x128) = We_enc @ Wm1[128:144]
// ball(128) = bm1 + be @ Wm1[128:144]
__global__ __launch_bounds__(256) void k_precomp(const float* __restrict__ Wm1, const float* __restrict__ bm1,
                                                 const float* __restrict__ Wm2, const float* __restrict__ bm2,
                                                 const float* __restrict__ Wu,
                                                 const float* __restrict__ We, const float* __restrict__ be,
                                                 float* __restrict__ Wupd, float* __restrict__ Wcomb,
                                                 float* __restrict__ c0, float* __restrict__ Wec,
                                                 float* __restrict__ ball) {
  int idx = blockIdx.x*256 + threadIdx.x;
  if (idx < 4096) {
    int k = idx >> 6, j = idx & 63;
    Wupd[idx] = Wu[k*64 + j] + ((k == j) ? 1.f : 0.f);
  } else if (idx < 12288) {
    int i2 = idx - 4096;
    int k = i2 >> 6, j = i2 & 63;
    float s = 0.f;
    for (int i = 0; i < 128; ++i) s = fmaf(Wm2[k*128 + i], Wu[(64+i)*64 + j], s);
    Wcomb[i2] = s;
  } else if (idx < 12352) {
    int j = idx - 12288;
    float s = 0.f;
    for (int i = 0; i < 128; ++i) s = fmaf(bm2[i], Wu[(64+i)*64 + j], s);
    c0[j] = s;
  } else if (idx < 14400) {
    int i2 = idx - 12352;
    int k = i2 >> 7, j = i2 & 127;
    float s = 0.f;
    for (int i = 0; i < 16; ++i) s = fmaf(We[k*16 + i], Wm1[(128+i)*128 + j], s);
    Wec[i2] = s;
  } else if (idx < 14528) {
    int j = idx - 14400;
    float s = bm1[j];
    for (int i = 0; i < 16; ++i) s = fmaf(be[i], Wm1[(128+i)*128 + j], s);
    ball[j] = s;
  }
}

// ---------- A(32768x256) = h @ [Wm1[0:64] | Wm1[64:128]]  (cols 0-127 = from-part, 128-255 = to-part) ----------
__global__ __launch_bounds__(256) void k_agemm(const float* __restrict__ h,
                                               const float* __restrict__ Wm1,
                                               float* __restrict__ A) {
  __shared__ __align__(16) float W_s[64*256];
  __shared__ __align__(16) float h_s[32*64];
  int tid = threadIdx.x;
  for (int idx = tid; idx < 64*256; idx += 256) {
    int k = idx >> 8, j = idx & 255;
    W_s[idx] = (j < 128) ? Wm1[k*128 + j] : Wm1[(64+k)*128 + (j-128)];
  }
  int base = blockIdx.x * 32;
  for (int idx = tid; idx < 32*64; idx += 256) h_s[idx] = h[base*64 + idx];
  __syncthreads();
  int cg = tid & 63;   // cols 4cg..4cg+3
  int ng = tid >> 6;   // nodes ng, ng+4, ..., ng+28
  float4 acc[8];
  #pragma unroll
  for (int i = 0; i < 8; ++i) acc[i] = make_float4(0,0,0,0);
  for (int k4 = 0; k4 < 16; ++k4) {
    float4 w[4];
    #pragma unroll
    for (int q = 0; q < 4; ++q) w[q] = ld4(&W_s[(k4*4+q)*256 + 4*cg]);
    #pragma unroll
    for (int i = 0; i < 8; ++i) {
      float4 h4 = ld4(&h_s[(ng + 4*i)*64 + k4*4]);
      fma4(acc[i], h4.x, w[0]); fma4(acc[i], h4.y, w[1]);
      fma4(acc[i], h4.z, w[2]); fma4(acc[i], h4.w, w[3]);
    }
  }
  #pragma unroll
  for (int i = 0; i < 8; ++i) {
    int n = base + ng + 4*i;
    st4(&A[n*256 + 4*cg], acc[i]);
  }
}

// ---------- per-node aggregation u[v] = sum_{e->v} relu(A_f[from] + A_t[v] + ef@Wec + ball) ----------
__global__ __launch_bounds__(128) void k_aggregate(const float* __restrict__ A,
                                                   const int* __restrict__ rowptr,
                                                   const int2* __restrict__ csr,
                                                   const float* __restrict__ ef,
                                                   const float* __restrict__ Wec,
                                                   const float* __restrict__ ball,
                                                   float* __restrict__ u) {
  int j = threadIdx.x;  // 0..127
  float wec[16];
  #pragma unroll
  for (int k = 0; k < 16; ++k) wec[k] = Wec[k*128 + j];
  float b = ball[j];
  int v0 = blockIdx.x * 8;
  for (int v = v0; v < v0 + 8; ++v) {
    float atvb = A[v*256 + 128 + j] + b;
    int s0 = rowptr[v], s1 = rowptr[v+1];
    float acc = 0.f;
    for (int s = s0; s < s1; ++s) {
      int2 fe = csr[s];
      const float4* efr = reinterpret_cast<const float4*>(ef) + (size_t)fe.y * 4;
      float4 e0 = efr[0], e1 = efr[1], e2 = efr[2], e3 = efr[3];
      float t = atvb + A[fe.x*256 + j];
      t = fmaf(e0.x, wec[0], t);  t = fmaf(e0.y, wec[1], t);
      t = fmaf(e0.z, wec[2], t);  t = fmaf(e0.w, wec[3], t);
      t = fmaf(e1.x, wec[4], t);  t = fmaf(e1.y, wec[5], t);
      t = fmaf(e1.z, wec[6], t);  t = fmaf(e1.w, wec[7], t);
      t = fmaf(e2.x, wec[8], t);  t = fmaf(e2.y, wec[9], t);
      t = fmaf(e2.z, wec[10], t); t = fmaf(e2.w, wec[11], t);
      t = fmaf(e3.x, wec[12], t); t = fmaf(e3.y, wec[13], t);
      t = fmaf(e3.z, wec[14], t); t = fmaf(e3.w, wec[15], t);
      acc += fmaxf(t, 0.f);
    }
    u[v*128 + j] = acc;
  }
}

// ---------- h_out = h@Wupd + u@Wcomb + deg*c0 + bu ----------
__global__ __launch_bounds__(256) void k_update(const float* __restrict__ h, const float* __restrict__ u,
                                                const int* __restrict__ deg,
                                                const float* __restrict__ Wupd, const float* __restrict__ Wcomb,
                                                const float* __restrict__ c0, const float* __restrict__ bu,
                                                float* __restrict__ hout) {
  __shared__ __align__(16) float Wall_s[192*64];  // rows 0-63 Wupd, 64-191 Wcomb
  __shared__ __align__(16) float h_s[32*64];
  __shared__ __align__(16) float u_s[32*128];
  int tid = threadIdx.x;
  for (int idx = tid; idx < 4096; idx += 256) Wall_s[idx] = Wupd[idx];
  for (int idx = tid; idx < 8192; idx += 256) Wall_s[4096 + idx] = Wcomb[idx];
  int base = blockIdx.x * 32;
  for (int idx = tid; idx < 2048; idx += 256) h_s[idx] = h[base*64 + idx];
  for (int idx = tid; idx < 4096; idx += 256) u_s[idx] = u[base*128 + idx];
  __syncthreads();
  int cg = tid & 15;   // cols 4cg..4cg+3 of 64
  int nl = tid >> 4;   // nodes nl, nl+16
  float4 acc[2];
  acc[0] = make_float4(0,0,0,0); acc[1] = make_float4(0,0,0,0);
  for (int k4 = 0; k4 < 16; ++k4) {
    float4 w[4];
    #pragma unroll
    for (int q = 0; q < 4; ++q) w[q] = ld4(&Wall_s[(k4*4+q)*64 + 4*cg]);
    #pragma unroll
    for (int i = 0; i < 2; ++i) {
      float4 h4 = ld4(&h_s[(nl + 16*i)*64 + k4*4]);
      fma4(acc[i], h4.x, w[0]); fma4(acc[i], h4.y, w[1]);
      fma4(acc[i], h4.z, w[2]); fma4(acc[i], h4.w, w[3]);
    }
  }
  for (int k4 = 0; k4 < 32; ++k4) {
    float4 w[4];
    #pragma unroll
    for (int q = 0; q < 4; ++q) w[q] = ld4(&Wall_s[(64 + k4*4+q)*64 + 4*cg]);
    #pragma unroll
    for (int i = 0; i < 2; ++i) {
      float4 u4 = ld4(&u_s[(nl + 16*i)*128 + k4*4]);
      fma4(acc[i], u4.x, w[0]); fma4(acc[i], u4.y, w[1]);
      fma4(acc[i], u4.z, w[2]); fma4(acc[i], u4.w, w[3]);
    }
  }
  float4 c04 = ld4(c0 + 4*cg);
  float4 bu4 = ld4(bu + 4*cg);
  #pragma unroll
  for (int i = 0; i < 2; ++i) {
    int n = base + nl + 16*i;
    float dg = (float)deg[n];
    float4 r = acc[i];
    r.x += dg*c04.x + bu4.x; r.y += dg*c04.y + bu4.y;
    r.z += dg*c04.z + bu4.z; r.w += dg*c04.w + bu4.w;
    st4(&hout[n*64 + 4*cg], r);
  }
}

// ---------- per-graph: g = h@Wa+ba; gv[g] = sum_n sigmoid(g[:,:128])*g[:,128:] ----------
__global__ __launch_bounds__(256) void k_gate(const float* __restrict__ h,
                                              const float* __restrict__ Wa, const float* __restrict__ ba,
                                              float* __restrict__ gv) {
  __shared__ __align__(16) float Wa_s[64*256];  // 64KB
  __shared__ __align__(16) float h_s[32*64];    // 8KB
  __shared__ __align__(16) float4 part_s[8][32];// 4KB
  int tid = threadIdx.x;
  int g = blockIdx.x;
  for (int idx = tid; idx < 64*256; idx += 256) Wa_s[idx] = Wa[idx];
  for (int idx = tid; idx < 2048; idx += 256) h_s[idx] = h[g*2048 + idx];
  __syncthreads();
  int cg = tid & 31;   // cols 4cg..4cg+3 (first half), +128 (second half)
  int nl = tid >> 5;   // nodes nl, nl+8, nl+16, nl+24
  float4 aA[4], aB[4];
  #pragma unroll
  for (int i = 0; i < 4; ++i) { aA[i] = make_float4(0,0,0,0); aB[i] = make_float4(0,0,0,0); }
  for (int k4 = 0; k4 < 16; ++k4) {
    float4 wa[4], wb[4];
    #pragma unroll
    for (int q = 0; q < 4; ++q) {
      wa[q] = ld4(&Wa_s[(k4*4+q)*256 + 4*cg]);
      wb[q] = ld4(&Wa_s[(k4*4+q)*256 + 128 + 4*cg]);
    }
    #pragma unroll
    for (int i = 0; i < 4; ++i) {
      float4 h4 = ld4(&h_s[(nl + 8*i)*64 + k4*4]);
      fma4(aA[i], h4.x, wa[0]); fma4(aA[i], h4.y, wa[1]); fma4(aA[i], h4.z, wa[2]); fma4(aA[i], h4.w, wa[3]);
      fma4(aB[i], h4.x, wb[0]); fma4(aB[i], h4.y, wb[1]); fma4(aB[i], h4.z, wb[2]); fma4(aB[i], h4.w, wb[3]);
    }
  }
  float4 ba4a = ld4(ba + 4*cg);
  float4 ba4b = ld4(ba + 128 + 4*cg);
  float4 sum = make_float4(0,0,0,0);
  #pragma unroll
  for (int i = 0; i < 4; ++i) {
    float ax = aA[i].x + ba4a.x, ay = aA[i].y + ba4a.y, az = aA[i].z + ba4a.z, aw = aA[i].w + ba4a.w;
    float bx = aB[i].x + ba4b.x, by = aB[i].y + ba4b.y, bz = aB[i].z + ba4b.z, bw = aB[i].w + ba4b.w;
    sum.x += bx / (1.f + __expf(-ax));
    sum.y += by / (1.f + __expf(-ay));
    sum.z += bz / (1.f + __expf(-az));
    sum.w += bw / (1.f + __expf(-aw));
  }
  part_s[nl][cg] = sum;
  __syncthreads();
  if (tid < 32) {
    float4 s = part_s[0][tid];
    #pragma unroll
    for (int n = 1; n < 8; ++n) {
      float4 p = part_s[n][tid];
      s.x += p.x; s.y += p.y; s.z += p.z; s.w += p.w;
    }
    st4(&gv[g*128 + tid*4], s);
  }
}

// ---------- pairs: out[p] = -sum relu((gv[2p]-gv[2p+1]) @ Wg)  (bg cancels) ----------
__global__ __launch_bounds__(64) void k_hinge(const float* __restrict__ gv,
                                              const float* __restrict__ Wg,
                                              float* __restrict__ out) {
  __shared__ float d_s[128];
  int p = blockIdx.x, tid = threadIdx.x;
  d_s[tid]      = gv[(2*p)*128 + tid]      - gv[(2*p+1)*128 + tid];
  d_s[tid + 64] = gv[(2*p)*128 + 64 + tid] - gv[(2*p+1)*128 + 64 + tid];
  __syncthreads();
  float a0 = 0.f, a1 = 0.f;
  for (int k = 0; k < 128; ++k) {
    float d = d_s[k];
    a0 = fmaf(d, Wg[k*128 + tid], a0);
    a1 = fmaf(d, Wg[k*128 + 64 + tid], a1);
  }
  float r = fmaxf(a0, 0.f) + fmaxf(a1, 0.f);
  #pragma unroll
  for (int off = 32; off > 0; off >>= 1) r += __shfl_down(r, off, 64);
  if (tid == 0) out[p] = -r;
}

extern "C" void kernel_launch(void* const* d_in, const int* in_sizes, int n_in,
                              void* d_out, int out_size, void* d_ws, size_t ws_size,
                              hipStream_t stream) {
  const float* nf  = (const float*)d_in[0];
  const float* ef  = (const float*)d_in[1];
  const int*   from= (const int*)d_in[2];
  const int*   toi = (const int*)d_in[3];
  const float* Wn  = (const float*)d_in[5];
  const float* bn  = (const float*)d_in[6];
  const float* We  = (const float*)d_in[7];
  const float* be  = (const float*)d_in[8];
  const float* Wm1 = (const float*)d_in[9];
  const float* bm1 = (const float*)d_in[10];
  const float* Wm2 = (const float*)d_in[11];
  const float* bm2 = (const float*)d_in[12];
  const float* Wu  = (const float*)d_in[13];
  const float* bu  = (const float*)d_in[14];
  const float* Wa  = (const float*)d_in[15];
  const float* ba  = (const float*)d_in[16];
  const float* Wg  = (const float*)d_in[17];
  float* out = (float*)d_out;

  float* fb    = (float*)d_ws;
  float* h0    = fb;                    // 2,097,152
  float* h1    = h0 + 2097152;          // 2,097,152
  float* A     = h1 + 2097152;          // 8,388,608
  float* u     = A  + 8388608;          // 4,194,304
  float* gv    = u  + 4194304;          // 131,072
  float* Wupd  = gv + 131072;           // 4,096
  float* Wcomb = Wupd + 4096;           // 8,192
  float* c0    = Wcomb + 8192;          // 64
  float* Wec   = c0 + 64;               // 2,048
  float* ball  = Wec + 2048;            // 128
  int2*  csr   = (int2*)(ball + 128);   // NE int2
  int*   deg   = (int*)(csr + NE);      // NN
  int*   rowptr= deg + NN;              // NN+1
  int*   cursor= rowptr + NN + 1;       // NN

  hipMemsetAsync(deg, 0, (size_t)(NN + (NN+1) + NN) * sizeof(int), stream);

  k_node_enc<<<NN/4, 256, 0, stream>>>(nf, Wn, bn, h0);
  k_hist<<<NE/256, 256, 0, stream>>>(toi, deg);
  k_scan<<<1, 1024, 0, stream>>>(deg, rowptr);
  k_scatter<<<NE/256, 256, 0, stream>>>(from, toi, rowptr, cursor, csr);
  k_precomp<<<57, 256, 0, stream>>>(Wm1, bm1, Wm2, bm2, Wu, We, be, Wupd, Wcomb, c0, Wec, ball);

  const float* hc = h0;
  float* hn = h1;
  for (int s = 0; s < 3; ++s) {
    k_agemm<<<NN/32, 256, 0, stream>>>(hc, Wm1, A);
    k_aggregate<<<NN/8, 128, 0, stream>>>(A, rowptr, csr, ef, Wec, ball, u);
    k_update<<<NN/32, 256, 0, stream>>>(hc, u, deg, Wupd, Wcomb, c0, bu, hn);
    float* t = (float*)hc; hc = hn; hn = t;
  }
  k_gate<<<NG, 256, 0, stream>>>(hc, Wa, ba, gv);
  k_hinge<<<512, 64, 0, stream>>>(gv, Wg, out);
}

// Round 4
// 473.646 us; speedup vs baseline: 1.0134x; 1.0134x over previous
//
#include <hip/hip_runtime.h>

static constexpr int NN = 32768;   // nodes
static constexpr int NE = 262144;  // edges
static constexpr int NG = 1024;    // graphs

__device__ __forceinline__ float4 ld4(const float* p){ return *reinterpret_cast<const float4*>(p); }
__device__ __forceinline__ void st4(float* p, const float4 v){ *reinterpret_cast<float4*>(p) = v; }
__device__ __forceinline__ void fma4(float4& a, const float s, const float4 w){
  a.x = fmaf(s, w.x, a.x); a.y = fmaf(s, w.y, a.y); a.z = fmaf(s, w.z, a.z); a.w = fmaf(s, w.w, a.w);
}

// ---------- h0 = nf(32768x32) @ Wn(32x64) + bn ----------
__global__ __launch_bounds__(256) void k_node_enc(const float* __restrict__ nf,
                                                  const float* __restrict__ Wn,
                                                  const float* __restrict__ bn,
                                                  float* __restrict__ h) {
  __shared__ __align__(16) float Wn_s[32*64];
  int tid = threadIdx.x;
  for (int i = tid; i < 32*64; i += 256) Wn_s[i] = Wn[i];
  __syncthreads();
  int j = tid & 63, nl = tid >> 6;
  int n = blockIdx.x*4 + nl;
  const float* r = nf + n*32;
  float acc = bn[j];
  #pragma unroll
  for (int k = 0; k < 32; ++k) acc = fmaf(r[k], Wn_s[k*64+j], acc);
  h[n*64+j] = acc;
}

// ---------- degree histogram ----------
__global__ __launch_bounds__(256) void k_hist(const int* __restrict__ toi, int* __restrict__ deg) {
  int e = blockIdx.x*256 + threadIdx.x;
  atomicAdd(&deg[toi[e]], 1);
}

// ---------- exclusive scan of deg[32768] -> rowptr[32769], single block 1024 thr ----------
__global__ __launch_bounds__(1024) void k_scan(const int* __restrict__ deg, int* __restrict__ rowptr) {
  __shared__ int sums[1024];
  int t = threadIdx.x;
  int base = t * 32;
  int local[32];
  int s = 0;
  #pragma unroll
  for (int i = 0; i < 32; ++i) { local[i] = s; s += deg[base + i]; }
  sums[t] = s;
  __syncthreads();
  for (int off = 1; off < 1024; off <<= 1) {
    int tmp = (t >= off) ? sums[t - off] : 0;
    __syncthreads();
    sums[t] += tmp;
    __syncthreads();
  }
  int boff = sums[t] - s;   // exclusive across threads
  #pragma unroll
  for (int i = 0; i < 32; ++i) rowptr[base + i] = boff + local[i];
  if (t == 1023) rowptr[NN] = sums[1023];
}

// ---------- scatter edges into CSR buckets ----------
__global__ __launch_bounds__(256) void k_scatter(const int* __restrict__ from, const int* __restrict__ toi,
                                                 const int* __restrict__ rowptr, int* __restrict__ cursor,
                                                 int2* __restrict__ csr) {
  int e = blockIdx.x*256 + threadIdx.x;
  int v = toi[e];
  int pos = atomicAdd(&cursor[v], 1);
  csr[rowptr[v] + pos] = make_int2(from[e], e);
}

// ---------- SoA-ify CSR: fromArr[s] = csr[s].x ; efp[s][0:16] = ef[csr[s].y][0:16] ----------
__global__ __launch_bounds__(256) void k_permute(const int2* __restrict__ csr,
                                                 const float* __restrict__ ef,
                                                 int* __restrict__ fromArr,
                                                 float* __restrict__ efp) {
  int s = blockIdx.x*256 + threadIdx.x;
  int2 fe = csr[s];
  fromArr[s] = fe.x;
  const float4* src = reinterpret_cast<const float4*>(ef) + (size_t)fe.y * 4;
  float4* dst = reinterpret_cast<float4*>(efp) + (size_t)s * 4;
  float4 a = src[0], b = src[1], c = src[2], d = src[3];
  dst[0] = a; dst[1] = b; dst[2] = c; dst[3] = d;
}

// ---------- precompute folded small matrices ----------
// Wupd (64x64) = Wu[0:64] + I
// Wcomb(128x64) = Wm2 @ Wu[64:192]
// c0(64) = bm2 @ Wu[64:192]
// Wec(16x128) = We_enc @ Wm1[128:144]
// ball(128) = bm1 + be @ Wm1[128:144]
__global__ __launch_bounds__(256) void k_precomp(const float* __restrict__ Wm1, const float* __restrict__ bm1,
                                                 const float* __restrict__ Wm2, const float* __restrict__ bm2,
                                                 const float* __restrict__ Wu,
                                                 const float* __restrict__ We, const float* __restrict__ be,
                                                 float* __restrict__ Wupd, float* __restrict__ Wcomb,
                                                 float* __restrict__ c0, float* __restrict__ Wec,
                                                 float* __restrict__ ball) {
  int idx = blockIdx.x*256 + threadIdx.x;
  if (idx < 4096) {
    int k = idx >> 6, j = idx & 63;
    Wupd[idx] = Wu[k*64 + j] + ((k == j) ? 1.f : 0.f);
  } else if (idx < 12288) {
    int i2 = idx - 4096;
    int k = i2 >> 6, j = i2 & 63;
    float s = 0.f;
    for (int i = 0; i < 128; ++i) s = fmaf(Wm2[k*128 + i], Wu[(64+i)*64 + j], s);
    Wcomb[i2] = s;
  } else if (idx < 12352) {
    int j = idx - 12288;
    float s = 0.f;
    for (int i = 0; i < 128; ++i) s = fmaf(bm2[i], Wu[(64+i)*64 + j], s);
    c0[j] = s;
  } else if (idx < 14400) {
    int i2 = idx - 12352;
    int k = i2 >> 7, j = i2 & 127;
    float s = 0.f;
    for (int i = 0; i < 16; ++i) s = fmaf(We[k*16 + i], Wm1[(128+i)*128 + j], s);
    Wec[i2] = s;
  } else if (idx < 14528) {
    int j = idx - 14400;
    float s = bm1[j];
    for (int i = 0; i < 16; ++i) s = fmaf(be[i], Wm1[(128+i)*128 + j], s);
    ball[j] = s;
  }
}

// ---------- Af(32768x128) = h @ Wm1[0:64] ; Atb(32768x128) = h @ Wm1[64:128] + ball ----------
__global__ __launch_bounds__(256) void k_agemm(const float* __restrict__ h,
                                               const float* __restrict__ Wm1,
                                               const float* __restrict__ ball,
                                               float* __restrict__ Af,
                                               float* __restrict__ Atb) {
  __shared__ __align__(16) float W_s[64*256];
  __shared__ __align__(16) float h_s[32*64];
  int tid = threadIdx.x;
  for (int idx = tid; idx < 64*256; idx += 256) {
    int k = idx >> 8, j = idx & 255;
    W_s[idx] = (j < 128) ? Wm1[k*128 + j] : Wm1[(64+k)*128 + (j-128)];
  }
  int base = blockIdx.x * 32;
  for (int idx = tid; idx < 32*64; idx += 256) h_s[idx] = h[base*64 + idx];
  __syncthreads();
  int cg = tid & 63;   // cols 4cg..4cg+3 of 256
  int ng = tid >> 6;   // nodes ng, ng+4, ..., ng+28
  float4 acc[8];
  #pragma unroll
  for (int i = 0; i < 8; ++i) acc[i] = make_float4(0,0,0,0);
  for (int k4 = 0; k4 < 16; ++k4) {
    float4 w[4];
    #pragma unroll
    for (int q = 0; q < 4; ++q) w[q] = ld4(&W_s[(k4*4+q)*256 + 4*cg]);
    #pragma unroll
    for (int i = 0; i < 8; ++i) {
      float4 h4 = ld4(&h_s[(ng + 4*i)*64 + k4*4]);
      fma4(acc[i], h4.x, w[0]); fma4(acc[i], h4.y, w[1]);
      fma4(acc[i], h4.z, w[2]); fma4(acc[i], h4.w, w[3]);
    }
  }
  if (cg < 32) {
    #pragma unroll
    for (int i = 0; i < 8; ++i) {
      int n = base + ng + 4*i;
      st4(&Af[(size_t)n*128 + 4*cg], acc[i]);
    }
  } else {
    int col = 4*cg - 128;
    float4 b4 = ld4(ball + col);
    #pragma unroll
    for (int i = 0; i < 8; ++i) {
      int n = base + ng + 4*i;
      float4 r = acc[i];
      r.x += b4.x; r.y += b4.y; r.z += b4.z; r.w += b4.w;
      st4(&Atb[(size_t)n*128 + col], r);
    }
  }
}

// ---------- per-node aggregation u[v] = sum_{s in row v} relu(Af[from[s]] + Atb[v] + efp[s]@Wec) ----------
__device__ __forceinline__ float edot(const float* __restrict__ e, const float* wec) {
  float t = 0.f;
  #pragma unroll
  for (int k = 0; k < 16; k += 4) {
    float4 q = ld4(e + k);
    t = fmaf(q.x, wec[k],   t); t = fmaf(q.y, wec[k+1], t);
    t = fmaf(q.z, wec[k+2], t); t = fmaf(q.w, wec[k+3], t);
  }
  return t;
}

__global__ __launch_bounds__(128) void k_aggregate(const float* __restrict__ Af,
                                                   const float* __restrict__ Atb,
                                                   const int* __restrict__ rowptr,
                                                   const int* __restrict__ fromArr,
                                                   const float* __restrict__ efp,
                                                   const float* __restrict__ Wec,
                                                   float* __restrict__ u) {
  int j = threadIdx.x;  // 0..127
  float wec[16];
  #pragma unroll
  for (int k = 0; k < 16; ++k) wec[k] = Wec[k*128 + j];
  int v0 = blockIdx.x * 8;
  for (int v = v0; v < v0 + 8; ++v) {
    float atv = Atb[(size_t)v*128 + j];
    int s0 = rowptr[v], s1 = rowptr[v+1];
    float acc = 0.f;
    int s = s0;
    for (; s + 4 <= s1; s += 4) {
      int f0 = fromArr[s], f1 = fromArr[s+1], f2 = fromArr[s+2], f3 = fromArr[s+3];
      float a0 = Af[(size_t)f0*128 + j];
      float a1 = Af[(size_t)f1*128 + j];
      float a2 = Af[(size_t)f2*128 + j];
      float a3 = Af[(size_t)f3*128 + j];
      float t0 = edot(efp + (size_t)s*16,     wec) + atv + a0;
      float t1 = edot(efp + (size_t)(s+1)*16, wec) + atv + a1;
      float t2 = edot(efp + (size_t)(s+2)*16, wec) + atv + a2;
      float t3 = edot(efp + (size_t)(s+3)*16, wec) + atv + a3;
      acc += fmaxf(t0, 0.f) + fmaxf(t1, 0.f) + fmaxf(t2, 0.f) + fmaxf(t3, 0.f);
    }
    for (; s < s1; ++s) {
      int f = fromArr[s];
      float a = Af[(size_t)f*128 + j];
      float t = edot(efp + (size_t)s*16, wec) + atv + a;
      acc += fmaxf(t, 0.f);
    }
    u[(size_t)v*128 + j] = acc;
  }
}

// ---------- h_out = h@Wupd + u@Wcomb + deg*c0 + bu ----------
__global__ __launch_bounds__(256) void k_update(const float* __restrict__ h, const float* __restrict__ u,
                                                const int* __restrict__ deg,
                                                const float* __restrict__ Wupd, const float* __restrict__ Wcomb,
                                                const float* __restrict__ c0, const float* __restrict__ bu,
                                                float* __restrict__ hout) {
  __shared__ __align__(16) float Wall_s[192*64];  // rows 0-63 Wupd, 64-191 Wcomb
  __shared__ __align__(16) float h_s[32*64];
  __shared__ __align__(16) float u_s[32*128];
  int tid = threadIdx.x;
  for (int idx = tid; idx < 4096; idx += 256) Wall_s[idx] = Wupd[idx];
  for (int idx = tid; idx < 8192; idx += 256) Wall_s[4096 + idx] = Wcomb[idx];
  int base = blockIdx.x * 32;
  for (int idx = tid; idx < 2048; idx += 256) h_s[idx] = h[base*64 + idx];
  for (int idx = tid; idx < 4096; idx += 256) u_s[idx] = u[base*128 + idx];
  __syncthreads();
  int cg = tid & 15;   // cols 4cg..4cg+3 of 64
  int nl = tid >> 4;   // nodes nl, nl+16
  float4 acc[2];
  acc[0] = make_float4(0,0,0,0); acc[1] = make_float4(0,0,0,0);
  for (int k4 = 0; k4 < 16; ++k4) {
    float4 w[4];
    #pragma unroll
    for (int q = 0; q < 4; ++q) w[q] = ld4(&Wall_s[(k4*4+q)*64 + 4*cg]);
    #pragma unroll
    for (int i = 0; i < 2; ++i) {
      float4 h4 = ld4(&h_s[(nl + 16*i)*64 + k4*4]);
      fma4(acc[i], h4.x, w[0]); fma4(acc[i], h4.y, w[1]);
      fma4(acc[i], h4.z, w[2]); fma4(acc[i], h4.w, w[3]);
    }
  }
  for (int k4 = 0; k4 < 32; ++k4) {
    float4 w[4];
    #pragma unroll
    for (int q = 0; q < 4; ++q) w[q] = ld4(&Wall_s[(64 + k4*4+q)*64 + 4*cg]);
    #pragma unroll
    for (int i = 0; i < 2; ++i) {
      float4 u4 = ld4(&u_s[(nl + 16*i)*128 + k4*4]);
      fma4(acc[i], u4.x, w[0]); fma4(acc[i], u4.y, w[1]);
      fma4(acc[i], u4.z, w[2]); fma4(acc[i], u4.w, w[3]);
    }
  }
  float4 c04 = ld4(c0 + 4*cg);
  float4 bu4 = ld4(bu + 4*cg);
  #pragma unroll
  for (int i = 0; i < 2; ++i) {
    int n = base + nl + 16*i;
    float dg = (float)deg[n];
    float4 r = acc[i];
    r.x += dg*c04.x + bu4.x; r.y += dg*c04.y + bu4.y;
    r.z += dg*c04.z + bu4.z; r.w += dg*c04.w + bu4.w;
    st4(&hout[n*64 + 4*cg], r);
  }
}

// ---------- per-graph: g = h@Wa+ba; gv[g] = sum_n sigmoid(g[:,:128])*g[:,128:] ----------
__global__ __launch_bounds__(256) void k_gate(const float* __restrict__ h,
                                              const float* __restrict__ Wa, const float* __restrict__ ba,
                                              float* __restrict__ gv) {
  __shared__ __align__(16) float Wa_s[64*256];  // 64KB
  __shared__ __align__(16) float h_s[32*64];    // 8KB
  __shared__ __align__(16) float4 part_s[8][32];// 4KB
  int tid = threadIdx.x;
  int g = blockIdx.x;
  for (int idx = tid; idx < 64*256; idx += 256) Wa_s[idx] = Wa[idx];
  for (int idx = tid; idx < 2048; idx += 256) h_s[idx] = h[g*2048 + idx];
  __syncthreads();
  int cg = tid & 31;   // cols 4cg..4cg+3 (first half), +128 (second half)
  int nl = tid >> 5;   // nodes nl, nl+8, nl+16, nl+24
  float4 aA[4], aB[4];
  #pragma unroll
  for (int i = 0; i < 4; ++i) { aA[i] = make_float4(0,0,0,0); aB[i] = make_float4(0,0,0,0); }
  for (int k4 = 0; k4 < 16; ++k4) {
    float4 wa[4], wb[4];
    #pragma unroll
    for (int q = 0; q < 4; ++q) {
      wa[q] = ld4(&Wa_s[(k4*4+q)*256 + 4*cg]);
      wb[q] = ld4(&Wa_s[(k4*4+q)*256 + 128 + 4*cg]);
    }
    #pragma unroll
    for (int i = 0; i < 4; ++i) {
      float4 h4 = ld4(&h_s[(nl + 8*i)*64 + k4*4]);
      fma4(aA[i], h4.x, wa[0]); fma4(aA[i], h4.y, wa[1]); fma4(aA[i], h4.z, wa[2]); fma4(aA[i], h4.w, wa[3]);
      fma4(aB[i], h4.x, wb[0]); fma4(aB[i], h4.y, wb[1]); fma4(aB[i], h4.z, wb[2]); fma4(aB[i], h4.w, wb[3]);
    }
  }
  float4 ba4a = ld4(ba + 4*cg);
  float4 ba4b = ld4(ba + 128 + 4*cg);
  float4 sum = make_float4(0,0,0,0);
  #pragma unroll
  for (int i = 0; i < 4; ++i) {
    float ax = aA[i].x + ba4a.x, ay = aA[i].y + ba4a.y, az = aA[i].z + ba4a.z, aw = aA[i].w + ba4a.w;
    float bx = aB[i].x + ba4b.x, by = aB[i].y + ba4b.y, bz = aB[i].z + ba4b.z, bw = aB[i].w + ba4b.w;
    sum.x += bx / (1.f + __expf(-ax));
    sum.y += by / (1.f + __expf(-ay));
    sum.z += bz / (1.f + __expf(-az));
    sum.w += bw / (1.f + __expf(-aw));
  }
  part_s[nl][cg] = sum;
  __syncthreads();
  if (tid < 32) {
    float4 s = part_s[0][tid];
    #pragma unroll
    for (int n = 1; n < 8; ++n) {
      float4 p = part_s[n][tid];
      s.x += p.x; s.y += p.y; s.z += p.z; s.w += p.w;
    }
    st4(&gv[g*128 + tid*4], s);
  }
}

// ---------- pairs: out[p] = -sum relu((gv[2p]-gv[2p+1]) @ Wg)  (bg cancels) ----------
__global__ __launch_bounds__(64) void k_hinge(const float* __restrict__ gv,
                                              const float* __restrict__ Wg,
                                              float* __restrict__ out) {
  __shared__ float d_s[128];
  int p = blockIdx.x, tid = threadIdx.x;
  d_s[tid]      = gv[(2*p)*128 + tid]      - gv[(2*p+1)*128 + tid];
  d_s[tid + 64] = gv[(2*p)*128 + 64 + tid] - gv[(2*p+1)*128 + 64 + tid];
  __syncthreads();
  float a0 = 0.f, a1 = 0.f;
  for (int k = 0; k < 128; ++k) {
    float d = d_s[k];
    a0 = fmaf(d, Wg[k*128 + tid], a0);
    a1 = fmaf(d, Wg[k*128 + 64 + tid], a1);
  }
  float r = fmaxf(a0, 0.f) + fmaxf(a1, 0.f);
  #pragma unroll
  for (int off = 32; off > 0; off >>= 1) r += __shfl_down(r, off, 64);
  if (tid == 0) out[p] = -r;
}

extern "C" void kernel_launch(void* const* d_in, const int* in_sizes, int n_in,
                              void* d_out, int out_size, void* d_ws, size_t ws_size,
                              hipStream_t stream) {
  const float* nf  = (const float*)d_in[0];
  const float* ef  = (const float*)d_in[1];
  const int*   from= (const int*)d_in[2];
  const int*   toi = (const int*)d_in[3];
  const float* Wn  = (const float*)d_in[5];
  const float* bn  = (const float*)d_in[6];
  const float* We  = (const float*)d_in[7];
  const float* be  = (const float*)d_in[8];
  const float* Wm1 = (const float*)d_in[9];
  const float* bm1 = (const float*)d_in[10];
  const float* Wm2 = (const float*)d_in[11];
  const float* bm2 = (const float*)d_in[12];
  const float* Wu  = (const float*)d_in[13];
  const float* bu  = (const float*)d_in[14];
  const float* Wa  = (const float*)d_in[15];
  const float* ba  = (const float*)d_in[16];
  const float* Wg  = (const float*)d_in[17];
  float* out = (float*)d_out;

  float* fb    = (float*)d_ws;
  float* h0    = fb;                    // 2,097,152 floats
  float* h1    = h0 + 2097152;          // 2,097,152
  float* Af    = h1 + 2097152;          // 4,194,304
  float* Atb   = Af + 4194304;          // 4,194,304
  float* u     = Atb + 4194304;         // 4,194,304
  float* efp   = u  + 4194304;          // 4,194,304
  float* gv    = efp + 4194304;         // 131,072
  float* Wupd  = gv + 131072;           // 4,096
  float* Wcomb = Wupd + 4096;           // 8,192
  float* c0    = Wcomb + 8192;          // 64
  float* Wec   = c0 + 64;               // 2,048
  float* ball  = Wec + 2048;            // 128
  int2*  csr   = (int2*)(ball + 128);   // NE int2
  int*   fromArr = (int*)(csr + NE);    // NE
  int*   deg   = fromArr + NE;          // NN
  int*   rowptr= deg + NN;              // NN+1
  int*   cursor= rowptr + NN + 1;       // NN

  hipMemsetAsync(deg, 0, (size_t)(NN + (NN+1) + NN) * sizeof(int), stream);

  k_node_enc<<<NN/4, 256, 0, stream>>>(nf, Wn, bn, h0);
  k_hist<<<NE/256, 256, 0, stream>>>(toi, deg);
  k_scan<<<1, 1024, 0, stream>>>(deg, rowptr);
  k_scatter<<<NE/256, 256, 0, stream>>>(from, toi, rowptr, cursor, csr);
  k_permute<<<NE/256, 256, 0, stream>>>(csr, ef, fromArr, efp);
  k_precomp<<<57, 256, 0, stream>>>(Wm1, bm1, Wm2, bm2, Wu, We, be, Wupd, Wcomb, c0, Wec, ball);

  const float* hc = h0;
  float* hn = h1;
  for (int s = 0; s < 3; ++s) {
    k_agemm<<<NN/32, 256, 0, stream>>>(hc, Wm1, ball, Af, Atb);
    k_aggregate<<<NN/8, 128, 0, stream>>>(Af, Atb, rowptr, fromArr, efp, Wec, u);
    k_update<<<NN/32, 256, 0, stream>>>(hc, u, deg, Wupd, Wcomb, c0, bu, hn);
    float* t = (float*)hc; hc = hn; hn = t;
  }
  k_gate<<<NG, 256, 0, stream>>>(hc, Wa, ba, gv);
  k_hinge<<<512, 64, 0, stream>>>(gv, Wg, out);
}

// Round 5
// 458.137 us; speedup vs baseline: 1.0477x; 1.0339x over previous
//
#include <hip/hip_runtime.h>

static constexpr int NN = 32768;   // nodes
static constexpr int NE = 262144;  // edges
static constexpr int NG = 1024;    // graphs

__device__ __forceinline__ float4 ld4(const float* p){ return *reinterpret_cast<const float4*>(p); }
__device__ __forceinline__ void st4(float* p, const float4 v){ *reinterpret_cast<float4*>(p) = v; }
__device__ __forceinline__ void fma4(float4& a, const float s, const float4 w){
  a.x = fmaf(s, w.x, a.x); a.y = fmaf(s, w.y, a.y); a.z = fmaf(s, w.z, a.z); a.w = fmaf(s, w.w, a.w);
}

// ---------- fused setup: node_enc (blocks 0..8191) | hist (8192..9215) | precomp (9216..9272) ----------
__global__ __launch_bounds__(256) void k_setup(const float* __restrict__ nf, const float* __restrict__ Wn,
                                               const float* __restrict__ bn, float* __restrict__ h,
                                               const int* __restrict__ toi, int* __restrict__ deg,
                                               const float* __restrict__ Wm1, const float* __restrict__ bm1,
                                               const float* __restrict__ Wm2, const float* __restrict__ bm2,
                                               const float* __restrict__ Wu,
                                               const float* __restrict__ We, const float* __restrict__ be,
                                               float* __restrict__ Wupd, float* __restrict__ Wcomb,
                                               float* __restrict__ c0, float* __restrict__ Wec,
                                               float* __restrict__ ball) {
  int b = blockIdx.x;
  int tid = threadIdx.x;
  if (b < 8192) {
    // ---- node encoder: h = nf @ Wn + bn (4 nodes per block) ----
    __shared__ __align__(16) float Wn_s[32*64];
    for (int i = tid; i < 32*64; i += 256) Wn_s[i] = Wn[i];
    __syncthreads();
    int j = tid & 63, nl = tid >> 6;
    int n = b*4 + nl;
    const float* r = nf + n*32;
    float acc = bn[j];
    #pragma unroll
    for (int k = 0; k < 32; ++k) acc = fmaf(r[k], Wn_s[k*64+j], acc);
    h[n*64+j] = acc;
  } else if (b < 8192 + 1024) {
    // ---- degree histogram ----
    int e = (b - 8192)*256 + tid;
    atomicAdd(&deg[toi[e]], 1);
  } else {
    // ---- precompute folded small matrices ----
    int idx = (b - 9216)*256 + tid;
    if (idx < 4096) {
      int k = idx >> 6, j = idx & 63;
      Wupd[idx] = Wu[k*64 + j] + ((k == j) ? 1.f : 0.f);
    } else if (idx < 12288) {
      int i2 = idx - 4096;
      int k = i2 >> 6, j = i2 & 63;
      float s = 0.f;
      for (int i = 0; i < 128; ++i) s = fmaf(Wm2[k*128 + i], Wu[(64+i)*64 + j], s);
      Wcomb[i2] = s;
    } else if (idx < 12352) {
      int j = idx - 12288;
      float s = 0.f;
      for (int i = 0; i < 128; ++i) s = fmaf(bm2[i], Wu[(64+i)*64 + j], s);
      c0[j] = s;
    } else if (idx < 14400) {
      int i2 = idx - 12352;
      int k = i2 >> 7, j = i2 & 127;
      float s = 0.f;
      for (int i = 0; i < 16; ++i) s = fmaf(We[k*16 + i], Wm1[(128+i)*128 + j], s);
      Wec[i2] = s;
    } else if (idx < 14528) {
      int j = idx - 14400;
      float s = bm1[j];
      for (int i = 0; i < 16; ++i) s = fmaf(be[i], Wm1[(128+i)*128 + j], s);
      ball[j] = s;
    }
  }
}

// ---------- exclusive scan of deg[32768] -> rowptr[32769], single block 1024 thr ----------
__global__ __launch_bounds__(1024) void k_scan(const int* __restrict__ deg, int* __restrict__ rowptr) {
  __shared__ int sums[1024];
  int t = threadIdx.x;
  int base = t * 32;
  int local[32];
  int s = 0;
  #pragma unroll
  for (int i = 0; i < 32; ++i) { local[i] = s; s += deg[base + i]; }
  sums[t] = s;
  __syncthreads();
  for (int off = 1; off < 1024; off <<= 1) {
    int tmp = (t >= off) ? sums[t - off] : 0;
    __syncthreads();
    sums[t] += tmp;
    __syncthreads();
  }
  int boff = sums[t] - s;   // exclusive across threads
  #pragma unroll
  for (int i = 0; i < 32; ++i) rowptr[base + i] = boff + local[i];
  if (t == 1023) rowptr[NN] = sums[1023];
}

// ---------- scatter edges directly into SoA CSR: fromArr[slot], efp[slot] = ef[e] ----------
__global__ __launch_bounds__(256) void k_scatter(const int* __restrict__ from, const int* __restrict__ toi,
                                                 const int* __restrict__ rowptr, int* __restrict__ cursor,
                                                 const float* __restrict__ ef,
                                                 int* __restrict__ fromArr, float* __restrict__ efp) {
  int e = blockIdx.x*256 + threadIdx.x;
  int v = toi[e];
  int pos = atomicAdd(&cursor[v], 1);
  int slot = rowptr[v] + pos;
  fromArr[slot] = from[e];
  const float4* src = reinterpret_cast<const float4*>(ef) + (size_t)e * 4;
  float4* dst = reinterpret_cast<float4*>(efp) + (size_t)slot * 4;
  float4 a = src[0], b4 = src[1], c = src[2], d = src[3];
  dst[0] = a; dst[1] = b4; dst[2] = c; dst[3] = d;
}

// ---------- Af(32768x128) = h @ Wm1[0:64] ; Atb(32768x128) = h @ Wm1[64:128] + ball ----------
__global__ __launch_bounds__(256) void k_agemm(const float* __restrict__ h,
                                               const float* __restrict__ Wm1,
                                               const float* __restrict__ ball,
                                               float* __restrict__ Af,
                                               float* __restrict__ Atb) {
  __shared__ __align__(16) float W_s[64*256];
  __shared__ __align__(16) float h_s[32*64];
  int tid = threadIdx.x;
  for (int idx = tid; idx < 64*256; idx += 256) {
    int k = idx >> 8, j = idx & 255;
    W_s[idx] = (j < 128) ? Wm1[k*128 + j] : Wm1[(64+k)*128 + (j-128)];
  }
  int base = blockIdx.x * 32;
  for (int idx = tid; idx < 32*64; idx += 256) h_s[idx] = h[base*64 + idx];
  __syncthreads();
  int cg = tid & 63;   // cols 4cg..4cg+3 of 256
  int ng = tid >> 6;   // nodes ng, ng+4, ..., ng+28
  float4 acc[8];
  #pragma unroll
  for (int i = 0; i < 8; ++i) acc[i] = make_float4(0,0,0,0);
  for (int k4 = 0; k4 < 16; ++k4) {
    float4 w[4];
    #pragma unroll
    for (int q = 0; q < 4; ++q) w[q] = ld4(&W_s[(k4*4+q)*256 + 4*cg]);
    #pragma unroll
    for (int i = 0; i < 8; ++i) {
      float4 h4 = ld4(&h_s[(ng + 4*i)*64 + k4*4]);
      fma4(acc[i], h4.x, w[0]); fma4(acc[i], h4.y, w[1]);
      fma4(acc[i], h4.z, w[2]); fma4(acc[i], h4.w, w[3]);
    }
  }
  if (cg < 32) {
    #pragma unroll
    for (int i = 0; i < 8; ++i) {
      int n = base + ng + 4*i;
      st4(&Af[(size_t)n*128 + 4*cg], acc[i]);
    }
  } else {
    int col = 4*cg - 128;
    float4 b4 = ld4(ball + col);
    #pragma unroll
    for (int i = 0; i < 8; ++i) {
      int n = base + ng + 4*i;
      float4 r = acc[i];
      r.x += b4.x; r.y += b4.y; r.z += b4.z; r.w += b4.w;
      st4(&Atb[(size_t)n*128 + col], r);
    }
  }
}

// ---------- per-node aggregation u[v] = sum_{s in row v} relu(Af[from[s]] + Atb[v] + efp[s]@Wec) ----------
__device__ __forceinline__ float edot(const float* __restrict__ e, const float* wec) {
  float t = 0.f;
  #pragma unroll
  for (int k = 0; k < 16; k += 4) {
    float4 q = ld4(e + k);
    t = fmaf(q.x, wec[k],   t); t = fmaf(q.y, wec[k+1], t);
    t = fmaf(q.z, wec[k+2], t); t = fmaf(q.w, wec[k+3], t);
  }
  return t;
}

__global__ __launch_bounds__(128) void k_aggregate(const float* __restrict__ Af,
                                                   const float* __restrict__ Atb,
                                                   const int* __restrict__ rowptr,
                                                   const int* __restrict__ fromArr,
                                                   const float* __restrict__ efp,
                                                   const float* __restrict__ Wec,
                                                   float* __restrict__ u) {
  int j = threadIdx.x;  // 0..127
  float wec[16];
  #pragma unroll
  for (int k = 0; k < 16; ++k) wec[k] = Wec[k*128 + j];
  int v0 = blockIdx.x * 8;
  for (int v = v0; v < v0 + 8; ++v) {
    float atv = Atb[(size_t)v*128 + j];
    int s0 = rowptr[v], s1 = rowptr[v+1];
    float acc = 0.f;
    int s = s0;
    // chunk of 8: issue all 8 gathers back-to-back for max memory-level parallelism
    for (; s + 8 <= s1; s += 8) {
      int f0 = fromArr[s],   f1 = fromArr[s+1], f2 = fromArr[s+2], f3 = fromArr[s+3];
      int f4 = fromArr[s+4], f5 = fromArr[s+5], f6 = fromArr[s+6], f7 = fromArr[s+7];
      float a0 = Af[(size_t)f0*128 + j];
      float a1 = Af[(size_t)f1*128 + j];
      float a2 = Af[(size_t)f2*128 + j];
      float a3 = Af[(size_t)f3*128 + j];
      float a4 = Af[(size_t)f4*128 + j];
      float a5 = Af[(size_t)f5*128 + j];
      float a6 = Af[(size_t)f6*128 + j];
      float a7 = Af[(size_t)f7*128 + j];
      float t0 = edot(efp + (size_t)s*16,      wec);
      float t1 = edot(efp + (size_t)(s+1)*16,  wec);
      float t2 = edot(efp + (size_t)(s+2)*16,  wec);
      float t3 = edot(efp + (size_t)(s+3)*16,  wec);
      float t4 = edot(efp + (size_t)(s+4)*16,  wec);
      float t5 = edot(efp + (size_t)(s+5)*16,  wec);
      float t6 = edot(efp + (size_t)(s+6)*16,  wec);
      float t7 = edot(efp + (size_t)(s+7)*16,  wec);
      acc += fmaxf(t0 + atv + a0, 0.f) + fmaxf(t1 + atv + a1, 0.f)
           + fmaxf(t2 + atv + a2, 0.f) + fmaxf(t3 + atv + a3, 0.f)
           + fmaxf(t4 + atv + a4, 0.f) + fmaxf(t5 + atv + a5, 0.f)
           + fmaxf(t6 + atv + a6, 0.f) + fmaxf(t7 + atv + a7, 0.f);
    }
    for (; s + 4 <= s1; s += 4) {
      int f0 = fromArr[s], f1 = fromArr[s+1], f2 = fromArr[s+2], f3 = fromArr[s+3];
      float a0 = Af[(size_t)f0*128 + j];
      float a1 = Af[(size_t)f1*128 + j];
      float a2 = Af[(size_t)f2*128 + j];
      float a3 = Af[(size_t)f3*128 + j];
      float t0 = edot(efp + (size_t)s*16,     wec);
      float t1 = edot(efp + (size_t)(s+1)*16, wec);
      float t2 = edot(efp + (size_t)(s+2)*16, wec);
      float t3 = edot(efp + (size_t)(s+3)*16, wec);
      acc += fmaxf(t0 + atv + a0, 0.f) + fmaxf(t1 + atv + a1, 0.f)
           + fmaxf(t2 + atv + a2, 0.f) + fmaxf(t3 + atv + a3, 0.f);
    }
    for (; s < s1; ++s) {
      int f = fromArr[s];
      float a = Af[(size_t)f*128 + j];
      float t = edot(efp + (size_t)s*16, wec);
      acc += fmaxf(t + atv + a, 0.f);
    }
    u[(size_t)v*128 + j] = acc;
  }
}

// ---------- h_out = h@Wupd + u@Wcomb + deg*c0 + bu ----------
__global__ __launch_bounds__(256) void k_update(const float* __restrict__ h, const float* __restrict__ u,
                                                const int* __restrict__ deg,
                                                const float* __restrict__ Wupd, const float* __restrict__ Wcomb,
                                                const float* __restrict__ c0, const float* __restrict__ bu,
                                                float* __restrict__ hout) {
  __shared__ __align__(16) float Wall_s[192*64];  // rows 0-63 Wupd, 64-191 Wcomb
  __shared__ __align__(16) float h_s[32*64];
  __shared__ __align__(16) float u_s[32*128];
  int tid = threadIdx.x;
  for (int idx = tid; idx < 4096; idx += 256) Wall_s[idx] = Wupd[idx];
  for (int idx = tid; idx < 8192; idx += 256) Wall_s[4096 + idx] = Wcomb[idx];
  int base = blockIdx.x * 32;
  for (int idx = tid; idx < 2048; idx += 256) h_s[idx] = h[base*64 + idx];
  for (int idx = tid; idx < 4096; idx += 256) u_s[idx] = u[base*128 + idx];
  __syncthreads();
  int cg = tid & 15;   // cols 4cg..4cg+3 of 64
  int nl = tid >> 4;   // nodes nl, nl+16
  float4 acc[2];
  acc[0] = make_float4(0,0,0,0); acc[1] = make_float4(0,0,0,0);
  for (int k4 = 0; k4 < 16; ++k4) {
    float4 w[4];
    #pragma unroll
    for (int q = 0; q < 4; ++q) w[q] = ld4(&Wall_s[(k4*4+q)*64 + 4*cg]);
    #pragma unroll
    for (int i = 0; i < 2; ++i) {
      float4 h4 = ld4(&h_s[(nl + 16*i)*64 + k4*4]);
      fma4(acc[i], h4.x, w[0]); fma4(acc[i], h4.y, w[1]);
      fma4(acc[i], h4.z, w[2]); fma4(acc[i], h4.w, w[3]);
    }
  }
  for (int k4 = 0; k4 < 32; ++k4) {
    float4 w[4];
    #pragma unroll
    for (int q = 0; q < 4; ++q) w[q] = ld4(&Wall_s[(64 + k4*4+q)*64 + 4*cg]);
    #pragma unroll
    for (int i = 0; i < 2; ++i) {
      float4 u4 = ld4(&u_s[(nl + 16*i)*128 + k4*4]);
      fma4(acc[i], u4.x, w[0]); fma4(acc[i], u4.y, w[1]);
      fma4(acc[i], u4.z, w[2]); fma4(acc[i], u4.w, w[3]);
    }
  }
  float4 c04 = ld4(c0 + 4*cg);
  float4 bu4 = ld4(bu + 4*cg);
  #pragma unroll
  for (int i = 0; i < 2; ++i) {
    int n = base + nl + 16*i;
    float dg = (float)deg[n];
    float4 r = acc[i];
    r.x += dg*c04.x + bu4.x; r.y += dg*c04.y + bu4.y;
    r.z += dg*c04.z + bu4.z; r.w += dg*c04.w + bu4.w;
    st4(&hout[n*64 + 4*cg], r);
  }
}

// ---------- per-graph: g = h@Wa+ba; gv[g] = sum_n sigmoid(g[:,:128])*g[:,128:] ----------
__global__ __launch_bounds__(256) void k_gate(const float* __restrict__ h,
                                              const float* __restrict__ Wa, const float* __restrict__ ba,
                                              float* __restrict__ gv) {
  __shared__ __align__(16) float Wa_s[64*256];  // 64KB
  __shared__ __align__(16) float h_s[32*64];    // 8KB
  __shared__ __align__(16) float4 part_s[8][32];// 4KB
  int tid = threadIdx.x;
  int g = blockIdx.x;
  for (int idx = tid; idx < 64*256; idx += 256) Wa_s[idx] = Wa[idx];
  for (int idx = tid; idx < 2048; idx += 256) h_s[idx] = h[g*2048 + idx];
  __syncthreads();
  int cg = tid & 31;   // cols 4cg..4cg+3 (first half), +128 (second half)
  int nl = tid >> 5;   // nodes nl, nl+8, nl+16, nl+24
  float4 aA[4], aB[4];
  #pragma unroll
  for (int i = 0; i < 4; ++i) { aA[i] = make_float4(0,0,0,0); aB[i] = make_float4(0,0,0,0); }
  for (int k4 = 0; k4 < 16; ++k4) {
    float4 wa[4], wb[4];
    #pragma unroll
    for (int q = 0; q < 4; ++q) {
      wa[q] = ld4(&Wa_s[(k4*4+q)*256 + 4*cg]);
      wb[q] = ld4(&Wa_s[(k4*4+q)*256 + 128 + 4*cg]);
    }
    #pragma unroll
    for (int i = 0; i < 4; ++i) {
      float4 h4 = ld4(&h_s[(nl + 8*i)*64 + k4*4]);
      fma4(aA[i], h4.x, wa[0]); fma4(aA[i], h4.y, wa[1]); fma4(aA[i], h4.z, wa[2]); fma4(aA[i], h4.w, wa[3]);
      fma4(aB[i], h4.x, wb[0]); fma4(aB[i], h4.y, wb[1]); fma4(aB[i], h4.z, wb[2]); fma4(aB[i], h4.w, wb[3]);
    }
  }
  float4 ba4a = ld4(ba + 4*cg);
  float4 ba4b = ld4(ba + 128 + 4*cg);
  float4 sum = make_float4(0,0,0,0);
  #pragma unroll
  for (int i = 0; i < 4; ++i) {
    float ax = aA[i].x + ba4a.x, ay = aA[i].y + ba4a.y, az = aA[i].z + ba4a.z, aw = aA[i].w + ba4a.w;
    float bx = aB[i].x + ba4b.x, by = aB[i].y + ba4b.y, bz = aB[i].z + ba4b.z, bw = aB[i].w + ba4b.w;
    sum.x += bx / (1.f + __expf(-ax));
    sum.y += by / (1.f + __expf(-ay));
    sum.z += bz / (1.f + __expf(-az));
    sum.w += bw / (1.f + __expf(-aw));
  }
  part_s[nl][cg] = sum;
  __syncthreads();
  if (tid < 32) {
    float4 s = part_s[0][tid];
    #pragma unroll
    for (int n = 1; n < 8; ++n) {
      float4 p = part_s[n][tid];
      s.x += p.x; s.y += p.y; s.z += p.z; s.w += p.w;
    }
    st4(&gv[g*128 + tid*4], s);
  }
}

// ---------- pairs: out[p] = -sum relu((gv[2p]-gv[2p+1]) @ Wg)  (bg cancels) ----------
__global__ __launch_bounds__(64) void k_hinge(const float* __restrict__ gv,
                                              const float* __restrict__ Wg,
                                              float* __restrict__ out) {
  __shared__ float d_s[128];
  int p = blockIdx.x, tid = threadIdx.x;
  d_s[tid]      = gv[(2*p)*128 + tid]      - gv[(2*p+1)*128 + tid];
  d_s[tid + 64] = gv[(2*p)*128 + 64 + tid] - gv[(2*p+1)*128 + 64 + tid];
  __syncthreads();
  float a0 = 0.f, a1 = 0.f;
  for (int k = 0; k < 128; ++k) {
    float d = d_s[k];
    a0 = fmaf(d, Wg[k*128 + tid], a0);
    a1 = fmaf(d, Wg[k*128 + 64 + tid], a1);
  }
  float r = fmaxf(a0, 0.f) + fmaxf(a1, 0.f);
  #pragma unroll
  for (int off = 32; off > 0; off >>= 1) r += __shfl_down(r, off, 64);
  if (tid == 0) out[p] = -r;
}

extern "C" void kernel_launch(void* const* d_in, const int* in_sizes, int n_in,
                              void* d_out, int out_size, void* d_ws, size_t ws_size,
                              hipStream_t stream) {
  const float* nf  = (const float*)d_in[0];
  const float* ef  = (const float*)d_in[1];
  const int*   from= (const int*)d_in[2];
  const int*   toi = (const int*)d_in[3];
  const float* Wn  = (const float*)d_in[5];
  const float* bn  = (const float*)d_in[6];
  const float* We  = (const float*)d_in[7];
  const float* be  = (const float*)d_in[8];
  const float* Wm1 = (const float*)d_in[9];
  const float* bm1 = (const float*)d_in[10];
  const float* Wm2 = (const float*)d_in[11];
  const float* bm2 = (const float*)d_in[12];
  const float* Wu  = (const float*)d_in[13];
  const float* bu  = (const float*)d_in[14];
  const float* Wa  = (const float*)d_in[15];
  const float* ba  = (const float*)d_in[16];
  const float* Wg  = (const float*)d_in[17];
  float* out = (float*)d_out;

  float* fb    = (float*)d_ws;
  float* h0    = fb;                    // 2,097,152 floats
  float* h1    = h0 + 2097152;          // 2,097,152
  float* Af    = h1 + 2097152;          // 4,194,304
  float* Atb   = Af + 4194304;          // 4,194,304
  float* u     = Atb + 4194304;         // 4,194,304
  float* efp   = u  + 4194304;          // 4,194,304
  float* gv    = efp + 4194304;         // 131,072
  float* Wupd  = gv + 131072;           // 4,096
  float* Wcomb = Wupd + 4096;           // 8,192
  float* c0    = Wcomb + 8192;          // 64
  float* Wec   = c0 + 64;               // 2,048
  float* ball  = Wec + 2048;            // 128
  int*   fromArr = (int*)(ball + 128);  // NE
  int*   deg   = fromArr + NE;          // NN
  int*   rowptr= deg + NN;              // NN+1
  int*   cursor= rowptr + NN + 1;       // NN

  hipMemsetAsync(deg, 0, (size_t)(NN + (NN+1) + NN) * sizeof(int), stream);

  k_setup<<<9273, 256, 0, stream>>>(nf, Wn, bn, h0, toi, deg,
                                    Wm1, bm1, Wm2, bm2, Wu, We, be,
                                    Wupd, Wcomb, c0, Wec, ball);
  k_scan<<<1, 1024, 0, stream>>>(deg, rowptr);
  k_scatter<<<NE/256, 256, 0, stream>>>(from, toi, rowptr, cursor, ef, fromArr, efp);

  const float* hc = h0;
  float* hn = h1;
  for (int s = 0; s < 3; ++s) {
    k_agemm<<<NN/32, 256, 0, stream>>>(hc, Wm1, ball, Af, Atb);
    k_aggregate<<<NN/8, 128, 0, stream>>>(Af, Atb, rowptr, fromArr, efp, Wec, u);
    k_update<<<NN/32, 256, 0, stream>>>(hc, u, deg, Wupd, Wcomb, c0, bu, hn);
    float* t = (float*)hc; hc = hn; hn = t;
  }
  k_gate<<<NG, 256, 0, stream>>>(hc, Wa, ba, gv);
  k_hinge<<<512, 64, 0, stream>>>(gv, Wg, out);
}